// Round 5
// baseline (110.527 us; speedup 1.0000x reference)
//
#include <hip/hip_runtime.h>
#include <math.h>

#define N_POINTS 16384
#define CELLS_PER_CLOUD 4096        // 16^3 per cloud, cell edge = r = 1/16
#define N_CELLS 32768               // 8 clouds
#define CAP 16                      // bucket capacity; lambda~0.5/cell, P(>16)~1e-12
#define NBR_STRIDE 32               // max neighbor count (established: cnt<=32)

constexpr double R2D = 1.0 / 256.0; // (1/16)^2, exact in binary

// Cell-occupancy counters live in .bss (zero-init at module load), NOT in the
// workspace: the harness re-poisons ws every iteration. k_conv_c re-zeros
// g_cnt after the last read (k_search_a), restoring the all-zeros invariant
// for the next iteration's k_prep. No memset dispatch needed.
__device__ int g_cnt[N_CELLS];

// ---------------------------------------------------------------------------
// K1: output copies (pos, batch->float) + cell-bucket build + pos4 pack.
// 64 blocks x 256 = N_POINTS threads (256 waves in flight; latency-bound
// atomic chain is concurrency-limited by wave count, not CU spread).
// ---------------------------------------------------------------------------
__global__ __launch_bounds__(256) void k_prep(const float* __restrict__ pos,
                                              const int* __restrict__ batch,
                                              float* __restrict__ out,
                                              float4* __restrict__ bucket,
                                              float4* __restrict__ pos4)
{
    int i = blockIdx.x * 256 + threadIdx.x;
    out[i]                = pos[i];                      // output 0: pos copy [N,3]
    out[i + N_POINTS]     = pos[i + N_POINTS];
    out[i + 2 * N_POINTS] = pos[i + 2 * N_POINTS];
    out[3 * N_POINTS + 32 * N_POINTS + i] = (float)batch[i];   // output 2

    float x = pos[3 * i], y = pos[3 * i + 1], z = pos[3 * i + 2];
    int ix = min(max((int)(x * 16.f), 0), 15);
    int iy = min(max((int)(y * 16.f), 0), 15);
    int iz = min(max((int)(z * 16.f), 0), 15);
    int cell = ((batch[i] * 16 + iz) * 16 + iy) * 16 + ix;
    pos4[i] = make_float4(x, y, z, __int_as_float(cell));
    int slot = atomicAdd(&g_cnt[cell], 1);
    if (slot < CAP) bucket[cell * CAP + slot] = make_float4(x, y, z, __int_as_float(i));
}

// ---------------------------------------------------------------------------
// K2: 27-cell radius search (fp64 test) fused with layer a (6->8->8).
// FLAT LIMIT: 32 threads per point, ONE cell each (g = 0..31, cells g<27).
// Block = 256 threads = 8 points x 32 groups; 2048 blocks -> 8 blocks/CU x
// 4 waves = 32 waves/CU (2x round-4). Per-thread chain: 1 cnt load + ~0.5
// dependent candidate loads — maximal memory-level parallelism for the
// scattered-latency-bound phase. Hits compact via LDS atomic; max-agg is
// exactly commutative -> hit-order nondeterminism changes no output bit.
// Layer-a tail: channel m = g for g<8, FMA order unchanged (bit-identical).
// ---------------------------------------------------------------------------
__global__ __launch_bounds__(256) void k_search_a(
    const float4* __restrict__ pos4, const float4* __restrict__ bucket,
    const float* __restrict__ W1, const float* __restrict__ b1,
    const float* __restrict__ W2, const float* __restrict__ b2,
    float* __restrict__ out_a, float4* __restrict__ nbr, int* __restrict__ nbr_cnt)
{
    __shared__ float sW1[48], sB1[8], sW2[64], sB2[8];
    __shared__ float4 s_hits[NBR_STRIDE][8];    // [slot][point] : 4 KB
    __shared__ int   s_k[8];
    __shared__ float s_mx[8][9];                // +1 pad

    int t = threadIdx.x;
    int p = t >> 5;          // point-in-block 0..7
    int g = t & 31;          // cell-group 0..31 (cells 0..26 active)

    if (t < 48) sW1[t] = W1[t];
    if (t < 8) { sB1[t] = b1[t]; sB2[t] = b2[t]; s_k[t] = 0; }
    if (t < 64) sW2[t] = W2[t];
    __syncthreads();

    int i = blockIdx.x * 8 + p;
    float4 pi4 = pos4[i];
    float xi = pi4.x, yi = pi4.y, zi = pi4.z;
    double xd = (double)xi, yd = (double)yi, zd = (double)zi;
    int cell0 = __float_as_int(pi4.w);
    int ix = cell0 & 15, iy = (cell0 >> 4) & 15, iz = (cell0 >> 8) & 15;
    int cb = cell0 & ~(CELLS_PER_CLOUD - 1);

    // --- this thread's single cell ---
    int dz = g / 9 - 1, dy = (g / 3) % 3 - 1, dx = g % 3 - 1;
    int zz = iz + dz, yy = iy + dy, xx = ix + dx;
    bool ok = (g < 27) & ((zz | yy | xx) >= 0) & (zz < 16) & (yy < 16) & (xx < 16);
    int zc = min(max(zz, 0), 15), yc = min(max(yy, 0), 15),
        xc = min(max(xx, 0), 15);
    int cid = cb + (zc << 8) + (yc << 4) + xc;       // always a valid address
    int nc = min(g_cnt[cid], CAP);                   // unconditional load
    int n = ok ? nc : 0;

    // --- candidate loop: load + fp64 test + LDS compact + global nbr store ---
    for (int s = 0; s < n; s++) {
        float4 q = bucket[cid * CAP + s];
        double ddx = xd - (double)q.x, ddy = yd - (double)q.y,
               ddz = zd - (double)q.z;
        double d2 = ddx * ddx + ddy * ddy + ddz * ddz;
        if (d2 <= R2D) {
            int slot = atomicAdd(&s_k[p], 1);
            if (slot < NBR_STRIDE) {
                s_hits[slot][p] = q;
                nbr[i * NBR_STRIDE + slot] = q;
            }
        }
    }
    __syncthreads();
    int kc = min(s_k[p], NBR_STRIDE);

    if (g == 0) nbr_cnt[i] = kc;

    // --- layer-a: channel m = g, for g < 8 ---
    if (g < 8) {
        float mxv = 0.f;                            // self always valid, relu >= 0
        for (int kk = 0; kk < kc; kk++) {
            float4 q = s_hits[kk][p];
            float in6[6] = { q.x, q.y, q.z, q.x - xi, q.y - yi, q.z - zi };
            float h = sB1[g];
#pragma unroll
            for (int c6 = 0; c6 < 6; c6++) h = fmaf(in6[c6], sW1[c6 * 8 + g], h);
            mxv = fmaxf(mxv, fmaxf(h, 0.f));
        }
        s_mx[p][g] = mxv;
    }
    __syncthreads();
    if (g < 8) {
        float o = sB2[g];
#pragma unroll
        for (int k = 0; k < 8; k++) o = fmaf(s_mx[p][k], sW2[k * 8 + g], o);
        out_a[i * 8 + g] = o > 0.f ? o : expm1f(o);   // celu, alpha=1
    }
}

// ---------------------------------------------------------------------------
// K3/K4: PointNetConv, LDS-staged gather then per-(point,channel) compute.
// ZERO_CNT (conv_c only): re-zero g_cnt for the next iteration — runs after
// k_search_a's last read; visibility to next dispatch guaranteed at kernel end.
// ---------------------------------------------------------------------------
template<int CIN4, int CMID, int PTS, bool ZERO_CNT>
__global__ __launch_bounds__(256) void k_conv(
    const float4* __restrict__ pos4, const float4* __restrict__ xin4,
    const float4* __restrict__ nbr, const int* __restrict__ nbr_cnt,
    const float* __restrict__ W1, const float* __restrict__ b1,
    const float* __restrict__ W2, const float* __restrict__ b2,
    float* __restrict__ xout)
{
    constexpr int CIN = CIN4 * 4;
    __shared__ float4 s_q[PTS][NBR_STRIDE];           // neighbor pos+id
    __shared__ float4 s_x[PTS][NBR_STRIDE][CIN4];     // gathered features
    __shared__ float  s_agg[PTS][CMID + 1];           // +1 pad

    int tid = threadIdx.x;

    if (ZERO_CNT) {
        int gid = blockIdx.x * 256 + tid;
        if (gid < N_CELLS) g_cnt[gid] = 0;
    }

    // ---- phase 1: parallel gather into LDS ----
#pragma unroll
    for (int w = tid; w < PTS * NBR_STRIDE; w += 256) {
        int sp = w >> 5, slot = w & 31;
        int si = blockIdx.x * PTS + sp;
        if (slot < nbr_cnt[si]) {
            float4 q = nbr[si * NBR_STRIDE + slot];
            s_q[sp][slot] = q;
            int j = __float_as_int(q.w);
#pragma unroll
            for (int k = 0; k < CIN4; k++) s_x[sp][slot][k] = xin4[j * CIN4 + k];
        }
    }
    __syncthreads();

    // ---- phase 2: per-(point, channel) compute from LDS ----
    int p = tid / CMID;
    int m = tid % CMID;
    int i = blockIdx.x * PTS + p;

    float4 pi = pos4[i];
    int cnt = nbr_cnt[i];

    float w1c[CIN + 3];
#pragma unroll
    for (int k = 0; k < CIN + 3; k++) w1c[k] = W1[k * CMID + m];
    float w2c[CMID];
#pragma unroll
    for (int k = 0; k < CMID; k++) w2c[k] = W2[k * CMID + m];
    float bb = b1[m];

    float mxv = 0.f;                                  // self always valid, relu >= 0
    for (int t = 0; t < cnt; t++) {
        float4 q = s_q[p][t];
        float h = bb;
#pragma unroll
        for (int k = 0; k < CIN4; k++) {
            float4 v = s_x[p][t][k];
            h = fmaf(v.x, w1c[4 * k],     h);
            h = fmaf(v.y, w1c[4 * k + 1], h);
            h = fmaf(v.z, w1c[4 * k + 2], h);
            h = fmaf(v.w, w1c[4 * k + 3], h);
        }
        h = fmaf(q.x - pi.x, w1c[CIN],     h);
        h = fmaf(q.y - pi.y, w1c[CIN + 1], h);
        h = fmaf(q.z - pi.z, w1c[CIN + 2], h);
        mxv = fmaxf(mxv, fmaxf(h, 0.f));
    }
    s_agg[p][m] = mxv;
    __syncthreads();

    float o = b2[m];
#pragma unroll
    for (int k = 0; k < CMID; k++) o = fmaf(s_agg[p][k], w2c[k], o);
    xout[i * CMID + m] = o > 0.f ? o : expm1f(o);     // celu, alpha=1
}

// ---------------------------------------------------------------------------
extern "C" void kernel_launch(void* const* d_in, const int* in_sizes, int n_in,
                              void* d_out, int out_size, void* d_ws, size_t ws_size,
                              hipStream_t stream)
{
    const float* pos   = (const float*)d_in[0];
    // d_in[1] = rgb: unused by reference
    const int*   batch = (const int*)d_in[2];
    const float* W1a = (const float*)d_in[3];
    const float* b1a = (const float*)d_in[4];
    const float* W2a = (const float*)d_in[5];
    const float* b2a = (const float*)d_in[6];
    const float* W1b = (const float*)d_in[7];
    const float* b1b = (const float*)d_in[8];
    const float* W2b = (const float*)d_in[9];
    const float* b2b = (const float*)d_in[10];
    const float* W1c = (const float*)d_in[11];
    const float* b1c = (const float*)d_in[12];
    const float* W2c = (const float*)d_in[13];
    const float* b2c = (const float*)d_in[14];

    float* out = (float*)d_out;

    char* ws = (char*)d_ws;
    size_t off = 0;
    auto alloc = [&](size_t bytes) {
        char* p = ws + off; off += (bytes + 255) & ~size_t(255); return p;
    };
    float4* bucket  = (float4*)alloc((size_t)N_CELLS * CAP * 16);
    float4* pos4    = (float4*)alloc(N_POINTS * 16);
    int*    nbr_cnt = (int*)alloc(N_POINTS * 4);
    float4* nbr     = (float4*)alloc((size_t)N_POINTS * NBR_STRIDE * 16);
    float*  out_a   = (float*)alloc(N_POINTS * 8 * 4);
    float*  out_b   = (float*)alloc(N_POINTS * 16 * 4);

    hipLaunchKernelGGL(k_prep, dim3(N_POINTS / 256), dim3(256), 0, stream,
                       pos, batch, out, bucket, pos4);
    hipLaunchKernelGGL(k_search_a, dim3(N_POINTS / 8), dim3(256), 0, stream,
                       pos4, bucket, W1a, b1a, W2a, b2a,
                       out_a, nbr, nbr_cnt);
    hipLaunchKernelGGL((k_conv<2, 16, 16, false>), dim3(N_POINTS / 16), dim3(256), 0, stream,
                       pos4, (const float4*)out_a, nbr, nbr_cnt,
                       W1b, b1b, W2b, b2b, out_b);
    hipLaunchKernelGGL((k_conv<4, 32, 8, true>), dim3(N_POINTS / 8), dim3(256), 0, stream,
                       pos4, (const float4*)out_b, nbr, nbr_cnt,
                       W1c, b1c, W2c, b2c, out + 3 * N_POINTS);
}